// Round 4
// baseline (148.567 us; speedup 1.0000x reference)
//
#include <hip/hip_runtime.h>
#include <hip/hip_bf16.h>

#define B_  128
#define J_  4096
#define D_  64
#define H_  128
#define E_  256
#define Z_  32

typedef __attribute__((ext_vector_type(8))) short short8;    // 8 bf16 (4 VGPRs)
typedef __attribute__((ext_vector_type(4))) float floatx4;   // MFMA C/D
typedef __attribute__((ext_vector_type(2))) float f2;        // v_pk_*_f32 pair

// workspace layout (bytes)
#define OFF_G      0u          // G' fp32 [4096][128] = 2 MiB
#define OFF_GSTATS 2097152u    // float4 per j        = 64 KiB
#define OFF_SCAL   2162688u    // {mean(w0), mean(w0^2)}
#define OFF_W0C    2162944u    // fp32[128]
#define OFF_C3     2163456u    // fp32[128] (= hbt1)
#define OFF_W2F    2163968u    // uint4[16][64] bf16 B-frags = 16 KiB
#define OFF_POOL   2180352u    // fp32[128][64] = 32 KiB

static __device__ __forceinline__ f2 mkf2(float a, float b) { f2 r; r.x = a; r.y = b; return r; }
static __device__ __forceinline__ f2 fma2(f2 a, f2 b, f2 c) { return __builtin_elementwise_fma(a, b, c); }
static __device__ __forceinline__ f2 max2(f2 a, f2 b) { return __builtin_elementwise_max(a, b); }

// RNE fp32->bf16 pack of two values: 2 VALU/elem + 1 v_perm_b32.
// result = (bf16(b) << 16) | bf16(a)  — matches __float22bfloat162_rn layout.
static __device__ __forceinline__ unsigned pk2(float a, float b) {
    unsigned ua = __builtin_bit_cast(unsigned, a);
    unsigned ub = __builtin_bit_cast(unsigned, b);
    ua += 0x7fffu + ((ua >> 16) & 1u);
    ub += 0x7fffu + ((ub >> 16) & 1u);
    return __builtin_amdgcn_perm(ub, ua, 0x07060302u);
}

// Sum over the 16 lanes of a DPP row (our C-layout row group), pure VALU:
// quad_perm xor1, quad_perm xor2 (full quad sums), row_ror:4, row_ror:8.
static __device__ __forceinline__ float row16_sum(float v) {
    int x;
    x = __builtin_amdgcn_update_dpp(0, __builtin_bit_cast(int, v), 0xB1,  0xf, 0xf, true);
    v += __builtin_bit_cast(float, x);
    x = __builtin_amdgcn_update_dpp(0, __builtin_bit_cast(int, v), 0x4E,  0xf, 0xf, true);
    v += __builtin_bit_cast(float, x);
    x = __builtin_amdgcn_update_dpp(0, __builtin_bit_cast(int, v), 0x124, 0xf, 0xf, true);
    v += __builtin_bit_cast(float, x);
    x = __builtin_amdgcn_update_dpp(0, __builtin_bit_cast(int, v), 0x128, 0xf, 0xf, true);
    v += __builtin_bit_cast(float, x);
    return v;
}

// ---------------------------------------------------------------------------
// pre_kernel (4105 blocks x 128): fuses g_kernel + prep + pooled-zero.
//  bid < 4096 : G'[j,h], Gstats[j] for j = bid
//  bid == 4096: scal, w0c, c3, W2 bf16 B-frag pack
//  bid > 4096 : zero pooled (8 blocks)
// ---------------------------------------------------------------------------
__global__ __launch_bounds__(128) void pre_kernel(
    const float* __restrict__ F, const float* __restrict__ hW1,
    const float* __restrict__ hb1, const float* __restrict__ hg1,
    const float* __restrict__ hbt1, const float* __restrict__ hW2,
    float* __restrict__ Gp, float4* __restrict__ Gstats,
    float* __restrict__ scal, float* __restrict__ w0c, float* __restrict__ c3,
    uint4* __restrict__ w2f, float4* __restrict__ pooled4)
{
    __shared__ float red[6];
    const int bid = blockIdx.x;
    const int t = threadIdx.x;

    if (bid >= 4097) {                       // zero pooled: 8 blocks x 256 float4
        const int base = (bid - 4097) * 256;
        pooled4[base + t]       = make_float4(0.f, 0.f, 0.f, 0.f);
        pooled4[base + 128 + t] = make_float4(0.f, 0.f, 0.f, 0.f);
        return;
    }

    if (bid == 4096) {                       // prep
        const float w0h = hW1[t];
        float s = w0h, q = w0h * w0h;
#pragma unroll
        for (int off = 32; off; off >>= 1) {
            s += __shfl_xor(s, off);
            q += __shfl_xor(q, off);
        }
        if ((t & 63) == 0) { red[(t >> 6) * 2] = s; red[(t >> 6) * 2 + 1] = q; }
        __syncthreads();
        const float mw0  = (red[0] + red[2]) * (1.f / (float)H_);
        const float ew02 = (red[1] + red[3]) * (1.f / (float)H_);
        if (t == 0) { scal[0] = mw0; scal[1] = ew02; }
        w0c[t] = (hW1[t] - mw0) * hg1[t];
        c3[t]  = hbt1[t];

        const int lane = t & 63, half = t >> 6;
        const int quad = lane >> 4, col = lane & 15;
        for (int f = half; f < 16; f += 2) {
            const int kstep = f >> 2, nt = f & 3;
            const int kbase = kstep * 32 + quad * 8;
            const int n = nt * 16 + col;
            unsigned r[4];
#pragma unroll
            for (int p = 0; p < 4; p++)
                r[p] = pk2(hW2[(kbase + 2*p) * D_ + n], hW2[(kbase + 2*p + 1) * D_ + n]);
            w2f[f * 64 + lane] = make_uint4(r[0], r[1], r[2], r[3]);
        }
        return;
    }

    // ---- g part: j = bid ----
    const int j = bid;
    const int h = t;
    const float* frow = F + (size_t)j * D_;
    float a0 = hb1[h], a1 = 0.f, a2 = 0.f, a3 = 0.f;
#pragma unroll
    for (int d = 0; d < D_; d += 4) {
        a0 = fmaf(frow[d + 0], hW1[(d + 1) * H_ + h], a0);
        a1 = fmaf(frow[d + 1], hW1[(d + 2) * H_ + h], a1);
        a2 = fmaf(frow[d + 2], hW1[(d + 3) * H_ + h], a2);
        a3 = fmaf(frow[d + 3], hW1[(d + 4) * H_ + h], a3);
    }
    const float acc = (a0 + a1) + (a2 + a3);

    const float w0h = hW1[h];
    float s1 = acc, s2 = w0h * acc, s3 = acc * acc;
#pragma unroll
    for (int off = 32; off; off >>= 1) {
        s1 += __shfl_xor(s1, off);
        s2 += __shfl_xor(s2, off);
        s3 += __shfl_xor(s3, off);
    }
    if ((h & 63) == 0) {
        int w = h >> 6;
        red[w*3+0] = s1; red[w*3+1] = s2; red[w*3+2] = s3;
    }
    __syncthreads();
    const float inv = 1.f / (float)H_;
    const float mG = (red[0] + red[3]) * inv;
    if (h == 0)
        Gstats[j] = make_float4(mG, (red[1]+red[4])*inv, (red[2]+red[5])*inv, 0.f);
    Gp[j * H_ + h] = (acc - mG) * hg1[h];
}

// ---------------------------------------------------------------------------
// main_kernel: per (b-group of BB, 16-row j-tile). Tile loads amortized over
// BB batch rows; packed-f32 LN1 H-build in A-frag layout; 16 MFMA vs
// register-held W2 B-frags; LN2 via DPP row sums (no DS pipe); masked pool.
// ---------------------------------------------------------------------------
#define TPW 2
#define BB  4

__global__ __launch_bounds__(256, 2) void main_kernel(
    const float* __restrict__ x, const int* __restrict__ mask,
    const float* __restrict__ Gp, const float4* __restrict__ Gstats,
    const float* __restrict__ scal,
    const float* __restrict__ w0c, const float* __restrict__ c3,
    const uint4* __restrict__ w2f,
    const float* __restrict__ hb2, const float* __restrict__ hg2,
    const float* __restrict__ hbt2,
    float* __restrict__ pooled)
{
    const int tid  = threadIdx.x;
    const int lane = tid & 63;
    const int wv   = tid >> 6;
    const int quad = lane >> 4;
    const int col  = lane & 15;
    const int b0   = blockIdx.y * BB;

    // ---- per-wave preload ----
    short8 w2r[16];
#pragma unroll
    for (int f = 0; f < 16; f++) {
        union { uint4 v; short8 s; } c; c.v = w2f[f * 64 + lane];
        w2r[f] = c.s;
    }
    f2 wc2[4][4], cc2[4][4];
#pragma unroll
    for (int k = 0; k < 4; k++) {
        const float4 wa = ((const float4*)(w0c + k*32 + quad*8))[0];
        const float4 wb = ((const float4*)(w0c + k*32 + quad*8))[1];
        wc2[k][0] = mkf2(wa.x, wa.y); wc2[k][1] = mkf2(wa.z, wa.w);
        wc2[k][2] = mkf2(wb.x, wb.y); wc2[k][3] = mkf2(wb.z, wb.w);
        const float4 ca = ((const float4*)(c3 + k*32 + quad*8))[0];
        const float4 cb = ((const float4*)(c3 + k*32 + quad*8))[1];
        cc2[k][0] = mkf2(ca.x, ca.y); cc2[k][1] = mkf2(ca.z, ca.w);
        cc2[k][2] = mkf2(cb.x, cb.y); cc2[k][3] = mkf2(cb.z, cb.w);
    }
    const f2 hb01 = mkf2(hb2[col],      hb2[16 + col]);
    const f2 hb23 = mkf2(hb2[32 + col], hb2[48 + col]);
    const f2 g201 = mkf2(hg2[col],      hg2[16 + col]);
    const f2 g223 = mkf2(hg2[32 + col], hg2[48 + col]);
    const f2 bt01 = mkf2(hbt2[col],      hbt2[16 + col]);
    const f2 bt23 = mkf2(hbt2[32 + col], hbt2[48 + col]);
    const float mw0s  = scal[0];
    const float ew02s = scal[1];
    const f2 z2 = mkf2(0.f, 0.f);

    f2 pool01[BB], pool23[BB];
#pragma unroll
    for (int bb = 0; bb < BB; bb++) { pool01[bb] = z2; pool23[bb] = z2; }

    for (int t = 0; t < TPW; t++) {
        const int tIdx = (blockIdx.x * 4 + wv) * TPW + t;
        const int j0   = tIdx * 16;
        const int rowA = j0 + col;

        // ---- tile loads (shared across BB batch rows) ----
        const float4 gs = Gstats[rowA];
        float xv[BB]; int4 mk[BB];
#pragma unroll
        for (int bb = 0; bb < BB; bb++) {
            xv[bb] = x[(size_t)(b0 + bb) * J_ + rowA];
            mk[bb] = *(const int4*)(mask + (size_t)(b0 + bb) * J_ + j0 + quad * 4);
        }
        const float* gpr = Gp + rowA * H_ + quad * 8;
        float4 ga4[4][2];
#pragma unroll
        for (int k = 0; k < 4; k++) {
            ga4[k][0] = ((const float4*)(gpr + k*32))[0];
            ga4[k][1] = ((const float4*)(gpr + k*32))[1];
        }

#pragma unroll
        for (int bb = 0; bb < BB; bb++) {
            const float xA = xv[bb];
            const float mean = fmaf(xA, mw0s, gs.x);
            const float eh2  = fmaf(xA, fmaf(xA, ew02s, 2.f * gs.y), gs.z);
            const float r1   = rsqrtf(fmaf(-mean, mean, eh2) + 1e-5f);
            const f2 x2v = mkf2(xA, xA);
            const f2 r1v = mkf2(r1, r1);

            floatx4 acc[4];
#pragma unroll
            for (int nt = 0; nt < 4; nt++) acc[nt] = (floatx4){0.f, 0.f, 0.f, 0.f};

#pragma unroll
            for (int k = 0; k < 4; k++) {
                const f2 t0 = fma2(x2v, wc2[k][0], mkf2(ga4[k][0].x, ga4[k][0].y));
                const f2 t1 = fma2(x2v, wc2[k][1], mkf2(ga4[k][0].z, ga4[k][0].w));
                const f2 t2 = fma2(x2v, wc2[k][2], mkf2(ga4[k][1].x, ga4[k][1].y));
                const f2 t3 = fma2(x2v, wc2[k][3], mkf2(ga4[k][1].z, ga4[k][1].w));
                const f2 h0 = max2(fma2(t0, r1v, cc2[k][0]), z2);
                const f2 h1 = max2(fma2(t1, r1v, cc2[k][1]), z2);
                const f2 h2 = max2(fma2(t2, r1v, cc2[k][2]), z2);
                const f2 h3 = max2(fma2(t3, r1v, cc2[k][3]), z2);
                union { unsigned u[4]; short8 s; } af;
                af.u[0] = pk2(h0.x, h0.y);
                af.u[1] = pk2(h1.x, h1.y);
                af.u[2] = pk2(h2.x, h2.y);
                af.u[3] = pk2(h3.x, h3.y);
                acc[0] = __builtin_amdgcn_mfma_f32_16x16x32_bf16(af.s, w2r[k*4+0], acc[0], 0, 0, 0);
                acc[1] = __builtin_amdgcn_mfma_f32_16x16x32_bf16(af.s, w2r[k*4+1], acc[1], 0, 0, 0);
                acc[2] = __builtin_amdgcn_mfma_f32_16x16x32_bf16(af.s, w2r[k*4+2], acc[2], 0, 0, 0);
                acc[3] = __builtin_amdgcn_mfma_f32_16x16x32_bf16(af.s, w2r[k*4+3], acc[3], 0, 0, 0);
            }

            // ---- epilogue: bias, LN2 stats via DPP row sums, relu, pool ----
            f2 y01[4], y23[4];
            float sa[4], qa[4];
#pragma unroll
            for (int r = 0; r < 4; r++) {
                y01[r] = mkf2(acc[0][r], acc[1][r]) + hb01;
                y23[r] = mkf2(acc[2][r], acc[3][r]) + hb23;
                const f2 s  = y01[r] + y23[r];
                const f2 qq = fma2(y01[r], y01[r], y23[r] * y23[r]);
                sa[r] = row16_sum(s.x + s.y);
                qa[r] = row16_sum(qq.x + qq.y);
            }
            float mrr[4];
            mrr[0] = (mk[bb].x > 0) ? 1.f : 0.f;
            mrr[1] = (mk[bb].y > 0) ? 1.f : 0.f;
            mrr[2] = (mk[bb].z > 0) ? 1.f : 0.f;
            mrr[3] = (mk[bb].w > 0) ? 1.f : 0.f;
#pragma unroll
            for (int r = 0; r < 4; r++) {
                const float m2 = sa[r] * (1.f / 64.f);
                const float v2 = fmaf(-m2, m2, qa[r] * (1.f / 64.f));
                const float rs = rsqrtf(v2 + 1e-5f);
                const f2 rsv  = mkf2(rs, rs);
                const f2 rg01 = rsv * g201;
                const f2 rg23 = rsv * g223;
                const f2 nm2  = mkf2(-m2, -m2);
                const f2 off01 = fma2(nm2, rg01, bt01);
                const f2 off23 = fma2(nm2, rg23, bt23);
                const f2 o01 = max2(fma2(y01[r], rg01, off01), z2);
                const f2 o23 = max2(fma2(y23[r], rg23, off23), z2);
                const f2 mr2 = mkf2(mrr[r], mrr[r]);
                pool01[bb] = fma2(mr2, o01, pool01[bb]);
                pool23[bb] = fma2(mr2, o23, pool23[bb]);
            }
        }
    }

    // reduce pools over the 4 quad-groups (rows) and write
#pragma unroll
    for (int m = 16; m < 64; m <<= 1) {
#pragma unroll
        for (int bb = 0; bb < BB; bb++) {
            pool01[bb].x += __shfl_xor(pool01[bb].x, m);
            pool01[bb].y += __shfl_xor(pool01[bb].y, m);
            pool23[bb].x += __shfl_xor(pool23[bb].x, m);
            pool23[bb].y += __shfl_xor(pool23[bb].y, m);
        }
    }
    if (lane < 16) {
#pragma unroll
        for (int bb = 0; bb < BB; bb++) {
            atomicAdd(&pooled[(size_t)(b0 + bb) * D_ +  0 + lane], pool01[bb].x);
            atomicAdd(&pooled[(size_t)(b0 + bb) * D_ + 16 + lane], pool01[bb].y);
            atomicAdd(&pooled[(size_t)(b0 + bb) * D_ + 32 + lane], pool23[bb].x);
            atomicAdd(&pooled[(size_t)(b0 + bb) * D_ + 48 + lane], pool23[bb].y);
        }
    }
}

// ---------------------------------------------------------------------------
// final_kernel: per-b head; computes cnt[b] from the mask row (coalesced).
// ---------------------------------------------------------------------------
__global__ __launch_bounds__(256) void final_kernel(
    const float* __restrict__ pooled, const int* __restrict__ mask,
    const float* __restrict__ eW1, const float* __restrict__ eb1,
    const float* __restrict__ eW2, const float* __restrict__ eb2,
    float* __restrict__ out)
{
    __shared__ float c_lds[D_];
    __shared__ float e_lds[E_];
    __shared__ float red[8];
    __shared__ float redc[4];
    const int b = blockIdx.x;
    const int t = threadIdx.x;
    const int lane = t & 63, wid = t >> 6;

    // count observed entries in this row (coalesced int4 reads)
    {
        const int4* mrow = (const int4*)(mask + (size_t)b * J_);
        int s = 0;
#pragma unroll
        for (int i = 0; i < 4; i++) {
            const int4 v = mrow[i * 256 + t];
            s += (v.x > 0) + (v.y > 0) + (v.z > 0) + (v.w > 0);
        }
        float fs = (float)s;
#pragma unroll
        for (int off = 32; off; off >>= 1) fs += __shfl_xor(fs, off);
        if (lane == 0) redc[wid] = fs;
    }
    __syncthreads();
    const float cn = fmaxf((redc[0] + redc[1]) + (redc[2] + redc[3]), 1.f);
    if (t < D_) c_lds[t] = pooled[(size_t)b * D_ + t] / cn;
    __syncthreads();

    // layer 1: 64 -> 256
    float acc = eb1[t];
#pragma unroll
    for (int d = 0; d < D_; d++)
        acc = fmaf(c_lds[d], eW1[(size_t)d * E_ + t], acc);

    float s = acc, s2 = acc * acc;
#pragma unroll
    for (int off = 32; off; off >>= 1) {
        s  += __shfl_xor(s, off);
        s2 += __shfl_xor(s2, off);
    }
    if ((t & 63) == 0) { red[wid * 2] = s; red[wid * 2 + 1] = s2; }
    __syncthreads();
    s  = red[0] + red[2] + red[4] + red[6];
    s2 = red[1] + red[3] + red[5] + red[7];
    const float m = s * (1.f / (float)E_);
    const float v = fmaf(-m, m, s2 * (1.f / (float)E_));
    const float r = rsqrtf(v + 1e-5f);
    e_lds[t] = fmaxf(0.f, (acc - m) * r);
    __syncthreads();

    // layer 2: 256 -> 64, first wave only
    if (t < 64) {
        float a2 = eb2[t];
#pragma unroll 8
        for (int k = 0; k < E_; k++)
            a2 = fmaf(e_lds[k], eW2[(size_t)k * 64 + t], a2);

        float u = a2, u2 = a2 * a2;
#pragma unroll
        for (int off = 32; off; off >>= 1) {
            u  += __shfl_xor(u, off);
            u2 += __shfl_xor(u2, off);
        }
        const float m2 = u * (1.f / 64.f);
        const float v2 = fmaf(-m2, m2, u2 * (1.f / 64.f));
        const float r2 = rsqrtf(v2 + 1e-5f);
        const float o  = fmaxf(0.f, (a2 - m2) * r2);
        if (t < Z_) out[(size_t)b * Z_ + t] = o;
        else        out[(size_t)B_ * Z_ + (size_t)b * Z_ + (t - Z_)] = o;
    }
}

// ---------------------------------------------------------------------------
extern "C" void kernel_launch(void* const* d_in, const int* in_sizes, int n_in,
                              void* d_out, int out_size, void* d_ws, size_t ws_size,
                              hipStream_t stream) {
    const float* x    = (const float*)d_in[0];
    const int*   mask = (const int*)d_in[1];
    const float* F    = (const float*)d_in[2];
    const float* hW1  = (const float*)d_in[3];
    const float* hb1  = (const float*)d_in[4];
    const float* hg1  = (const float*)d_in[5];
    const float* hbt1 = (const float*)d_in[6];
    const float* hW2  = (const float*)d_in[7];
    const float* hb2  = (const float*)d_in[8];
    const float* hg2  = (const float*)d_in[9];
    const float* hbt2 = (const float*)d_in[10];
    const float* eW1  = (const float*)d_in[11];
    const float* eb1  = (const float*)d_in[12];
    const float* eW2  = (const float*)d_in[13];
    const float* eb2  = (const float*)d_in[14];
    float* out = (float*)d_out;

    char* ws = (char*)d_ws;
    float*  Gp     = (float*)(ws + OFF_G);
    float4* Gstats = (float4*)(ws + OFF_GSTATS);
    float*  scal   = (float*)(ws + OFF_SCAL);
    float*  w0c    = (float*)(ws + OFF_W0C);
    float*  c3     = (float*)(ws + OFF_C3);
    uint4*  w2f    = (uint4*)(ws + OFF_W2F);
    float*  pooled = (float*)(ws + OFF_POOL);

    pre_kernel<<<J_ + 9, 128, 0, stream>>>(F, hW1, hb1, hg1, hbt1, hW2,
                                           Gp, Gstats, scal, w0c, c3, w2f,
                                           (float4*)pooled);
    main_kernel<<<dim3(J_ / (16 * 4 * TPW), B_ / BB), 256, 0, stream>>>(
        x, mask, Gp, Gstats, scal, w0c, c3, w2f, hb2, hg2, hbt2, pooled);
    final_kernel<<<B_, E_, 0, stream>>>(pooled, mask, eW1, eb1, eW2, eb2, out);
}